// Round 2
// baseline (187.282 us; speedup 1.0000x reference)
//
#include <hip/hip_runtime.h>

// FeedForwardQuantum: out = relu( (cos(theta)*cos(x@Wmap^T)) @ W1^T + b1 ) @ W2^T + b2
// ALL tensors fp32 (in_npz_mb=55.5 proves it). Compute path: fp32 -> bf16 MFMA.
//  kW2: W2 fp32 -> w2b bf16 [768][3072], 16B-chunk XOR-swizzled by (n&7) within 8-chunk groups.
//  kP : W1+b1 fp32 -> w1p bf16 [3072][32], wire10 = b1, chunks swizzled by (k&3).
//  kQ : q = cos(theta)*cos(x@Wmap^T) fp32 math -> qp bf16 [16384][32], swizzled, bias slot=1.0.
//  kG : per 64x384 tile: stage W2/W1/q via global_load_lds(16B); h-phase MFMA -> swizzled LDS;
//       main MFMA acc += h @ W2tile^T; fp32 epilogue (+b2).

typedef __attribute__((ext_vector_type(4))) float f32x4;
typedef __attribute__((ext_vector_type(8))) short bf16x8;

#define F_TOTAL 16384
#define E_DIM   768
#define FFN     3072

static __device__ __forceinline__ unsigned short f2bf(float f) {
    union { float f; unsigned int i; } v; v.f = f;
    unsigned int r = v.i + 0x7FFFu + ((v.i >> 16) & 1u);   // RNE
    return (unsigned short)(r >> 16);
}
static __device__ __forceinline__ void gload16(const void* g, void* l) {
    __builtin_amdgcn_global_load_lds((const __attribute__((address_space(1))) unsigned int*)g,
                                     (__attribute__((address_space(3))) unsigned int*)l,
                                     16, 0, 0);
}

// ---------------- kW2: W2 fp32 -> bf16, pre-swizzled ----------------
__global__ __launch_bounds__(384) void kW2(const float* __restrict__ w2,
                                           unsigned short* __restrict__ w2b) {
    const int n = (int)blockIdx.x;        // 768 rows
    const int c = (int)threadIdx.x;       // 384 chunks of 8
    const float4* src = (const float4*)(w2 + (size_t)n * FFN + c * 8);
    float4 a = src[0], b = src[1];
    bf16x8 v;
    v[0] = (short)f2bf(a.x); v[1] = (short)f2bf(a.y);
    v[2] = (short)f2bf(a.z); v[3] = (short)f2bf(a.w);
    v[4] = (short)f2bf(b.x); v[5] = (short)f2bf(b.y);
    v[6] = (short)f2bf(b.z); v[7] = (short)f2bf(b.w);
    *(bf16x8*)(w2b + (size_t)n * FFN + (size_t)(c ^ (n & 7)) * 8) = v;
}

// ---------------- kP: pack W1 + b1 -> w1p[3072][32] (swizzled) ----------------
__global__ void kP(const float* __restrict__ w1,
                   const float* __restrict__ b1,
                   unsigned short* __restrict__ w1p) {
    int k = blockIdx.x * 256 + threadIdx.x;
    if (k >= FFN) return;
    float r[32];
#pragma unroll
    for (int w = 0; w < 10; ++w) r[w] = w1[k * 10 + w];
    r[10] = b1[k];
#pragma unroll
    for (int w = 11; w < 32; ++w) r[w] = 0.f;
#pragma unroll
    for (int c = 0; c < 4; ++c) {
        bf16x8 v;
#pragma unroll
        for (int e = 0; e < 8; ++e) v[e] = (short)f2bf(r[c * 8 + e]);
        *(bf16x8*)(w1p + (size_t)k * 32 + (size_t)((c ^ (k & 3)) * 8)) = v;
    }
}

// ---------------- kQ: qp[16384][32] bf16 (swizzled, padded, bias slot) --------
__global__ __launch_bounds__(256) void kQ(const float* __restrict__ x,
                                          const float* __restrict__ wm,
                                          const float* __restrict__ th,
                                          unsigned short* __restrict__ qp) {
    const int tid = (int)threadIdx.x;
    const int wv = tid >> 6, l = tid & 63;
    const int m0 = (int)blockIdx.x * 24 + wv * 6;
    if (l < 60) {
        const int r6 = l / 10, w = l - r6 * 10;
        const int m = m0 + r6;
        if (m < F_TOTAL) {
            float ct = __cosf(th[w]);
            const float4* xp = (const float4*)(x + (size_t)m * E_DIM);
            const float4* wp = (const float4*)(wm + (size_t)w * E_DIM);
            float s0 = 0.f, s1 = 0.f, s2 = 0.f, s3 = 0.f;
#pragma unroll 4
            for (int j = 0; j < E_DIM / 4; ++j) {
                float4 a = xp[j], b = wp[j];
                s0 = fmaf(a.x, b.x, s0); s1 = fmaf(a.y, b.y, s1);
                s2 = fmaf(a.z, b.z, s2); s3 = fmaf(a.w, b.w, s3);
            }
            float q = ct * __cosf((s0 + s1) + (s2 + s3));
            qp[(size_t)m * 32 + (size_t)((((w >> 3) ^ (m & 3)) * 8) + (w & 7))] = f2bf(q);
        }
    } else if (l == 60) {
#pragma unroll
        for (int rr = 0; rr < 6; ++rr) {
            int m = m0 + rr;
            if (m < F_TOTAL)  // elem 10 (bias=1.0): chunk 1, offset 2
                qp[(size_t)m * 32 + (size_t)(((1 ^ (m & 3)) * 8) + 2)] = (unsigned short)0x3F80;
        }
    }
}

// ---------------- kG: fused h-compute + main GEMM -----------------------------
// 512 blocks, 512 threads (8 waves). BM=64, BN=384, BK=64.
// LDS = 48K(w2) + 8K(h) + 4K(q) + 4K(w1) = 64 KiB -> 2 blocks/CU.
__global__ __launch_bounds__(512, 4) void kG(const unsigned short* __restrict__ w2b,
                                             const float* __restrict__ b2,
                                             const unsigned short* __restrict__ qp,
                                             const unsigned short* __restrict__ w1p,
                                             float* __restrict__ outp) {
    __shared__ __align__(16) unsigned short w2s[384 * 64];  // [n][k] swz8 (pre-swizzled src)
    __shared__ __align__(16) unsigned short hs[64 * 64];    // [m][k] swz8
    __shared__ __align__(16) unsigned short qs[64 * 32];    // verbatim pre-swizzled qp rows
    __shared__ __align__(16) unsigned short w1s[64 * 32];   // verbatim pre-swizzled w1p rows

    const int tid = (int)threadIdx.x;
    const int wv = tid >> 6;
    const int l  = tid & 63;
    // chunked XCD swizzle: each XCD's 64 resident blocks share one W2 n-slab (2.25MB < 4MB L2)
    const int bid = (int)blockIdx.x;
    const int ld  = (bid & 7) * 64 + (bid >> 3);   // bijective, 512 blocks
    const int m0 = (ld & 255) * 64;
    const int n0 = (ld >> 8) * 384;

    // stage q rows once (4096 B, waves 0..3, 16B/lane, linear LDS dest)
    if (wv < 4) {
        const unsigned short* src = qp + (size_t)(m0 + (tid >> 2)) * 32 + (size_t)(tid & 3) * 8;
        gload16(src, qs + (size_t)wv * 512);
    }

    const f32x4 z4 = {0.f, 0.f, 0.f, 0.f};
    f32x4 acc[4][3];
#pragma unroll
    for (int a = 0; a < 4; ++a)
#pragma unroll
        for (int b = 0; b < 3; ++b) acc[a][b] = z4;

    const int mih = wv >> 1;      // wave's M-fragment block for h-phase
    const int r_w2 = tid >> 3;    // staging row (+64*i)
    const int c_w2 = tid & 7;     // staging 16B chunk (linear; swizzle pre-baked in w2b)
    bf16x8 aq;

    for (int kt = 0; kt < FFN / 64; ++kt) {
        const int k0 = kt * 64;
        if (wv < 4) {  // stage W1 rows k0..k0+63 verbatim (4096 B)
            const unsigned short* s1 = w1p + (size_t)(k0 + (tid >> 2)) * 32 + (size_t)(tid & 3) * 8;
            gload16(s1, w1s + (size_t)wv * 512);
        }
#pragma unroll
        for (int i = 0; i < 6; ++i) {  // stage W2 tile [384][64] (pre-swizzled source)
            int r = i * 64 + r_w2;
            const unsigned short* s2 = w2b + (size_t)(n0 + r) * FFN + k0 + (size_t)c_w2 * 8;
            gload16(s2, w2s + (size_t)i * 4096 + (size_t)wv * 512);
        }
        __syncthreads();

        if (kt == 0) {
            int qrow = mih * 16 + (l & 15);
            int qch = (l >> 4) ^ (qrow & 3);
            aq = *(const bf16x8*)(qs + qrow * 32 + qch * 8);
        }

        // ---- h phase: h[64][64] = relu(q @ W1c^T + b1) via MFMA ----
#pragma unroll
        for (int j = 0; j < 2; ++j) {
            int ki = (wv * 2 + j) & 3;
            int kw = ki * 16 + (l & 15);
            int cw = (l >> 4) ^ (kw & 3);
            bf16x8 bw = *(const bf16x8*)(w1s + kw * 32 + cw * 8);
            f32x4 hv = __builtin_amdgcn_mfma_f32_16x16x32_bf16(aq, bw, z4, 0, 0, 0);
            int kkc = ki * 16 + (l & 15);           // h column (K-local)
            int mb = mih * 16 + (l >> 4) * 4;       // h row base
#pragma unroll
            for (int jj = 0; jj < 4; ++jj) {
                int m = mb + jj;
                hs[m * 64 + (((kkc >> 3) ^ (m & 7)) * 8) + (kkc & 7)] =
                    f2bf(fmaxf(hv[jj], 0.f));
            }
        }
        __syncthreads();

        // ---- main phase: acc += h @ W2tile^T ----
#pragma unroll
        for (int kk2 = 0; kk2 < 2; ++kk2) {
            const int kc = kk2 * 4 + (l >> 4);
            bf16x8 af[4];
#pragma unroll
            for (int mi = 0; mi < 4; ++mi) {
                int m = mi * 16 + (l & 15);
                af[mi] = *(const bf16x8*)(hs + m * 64 + ((kc ^ (m & 7)) * 8));
            }
#pragma unroll
            for (int ni = 0; ni < 3; ++ni) {
                int n = wv * 48 + ni * 16 + (l & 15);
                bf16x8 bfr = *(const bf16x8*)(w2s + n * 64 + ((kc ^ (n & 7)) * 8));
#pragma unroll
                for (int mi = 0; mi < 4; ++mi)
                    acc[mi][ni] = __builtin_amdgcn_mfma_f32_16x16x32_bf16(af[mi], bfr, acc[mi][ni], 0, 0, 0);
            }
        }
        __syncthreads();
    }

    // epilogue: + b2, fp32 store
#pragma unroll
    for (int ni = 0; ni < 3; ++ni) {
        int n = n0 + wv * 48 + ni * 16 + (l & 15);
        float b2v = b2[n];
#pragma unroll
        for (int mi = 0; mi < 4; ++mi) {
            int mbase = m0 + mi * 16 + (l >> 4) * 4;
#pragma unroll
            for (int jj = 0; jj < 4; ++jj)
                outp[(size_t)(mbase + jj) * E_DIM + n] = acc[mi][ni][jj] + b2v;
        }
    }
}

extern "C" void kernel_launch(void* const* d_in, const int* in_sizes, int n_in,
                              void* d_out, int out_size, void* d_ws, size_t ws_size,
                              hipStream_t stream) {
    const float* x    = (const float*)d_in[0];
    const float* wmap = (const float*)d_in[1];
    const float* th   = (const float*)d_in[2];
    const float* w1   = (const float*)d_in[3];
    const float* b1   = (const float*)d_in[4];
    const float* w2   = (const float*)d_in[5];
    const float* b2   = (const float*)d_in[6];
    float* out = (float*)d_out;

    unsigned short* qp  = (unsigned short*)d_ws;            // 16384*32 bf16 = 1 MiB
    unsigned short* w1p = qp + (size_t)F_TOTAL * 32;        // 3072*32 bf16 = 192 KiB
    unsigned short* w2b = w1p + (size_t)FFN * 32;           // 768*3072 bf16 = 4.5 MiB

    (void)hipMemsetAsync(qp, 0, (size_t)F_TOTAL * 32 * sizeof(unsigned short), stream);
    kW2<<<E_DIM, 384, 0, stream>>>(w2, w2b);
    kP<<<(FFN + 255) / 256, 256, 0, stream>>>(w1, b1, w1p);
    kQ<<<(F_TOTAL + 23) / 24, 256, 0, stream>>>(x, wmap, th, qp);
    kG<<<512, 512, 0, stream>>>(w2b, b2, qp, w1p, out);
}

// Round 3
// 124.011 us; speedup vs baseline: 1.5102x; 1.5102x over previous
//
#include <hip/hip_runtime.h>

// FeedForwardQuantum: out = relu( (cos(theta)*cos(x@Wmap^T)) @ W1^T + b1 ) @ W2^T + b2
// ALL tensors fp32. Compute path: fp32 -> bf16 MFMA -> fp32 out.
//  kW2: W2 fp32 -> w2b bf16 [768][3072], 16B-chunk XOR-swizzled by (n&7).
//  kP : W1+b1 fp32 -> w1p bf16 [3072][32], wire10 = b1, chunks swizzled by (k&3).
//  kQ : coalesced wave-per-row: q = cos(theta)*cos(x@Wmap^T) -> qp bf16 [16384][32]
//       (swizzled; bias slot = 1.0; zero padding written by lanes 11..31 -> no memset).
//  kG : per 64x384 tile: stage W2/W1/q via global_load_lds(16B); h-phase MFMA -> swizzled LDS;
//       main MFMA acc += h @ W2tile^T; fp32 epilogue (+b2). (UNCHANGED from passing round.)

typedef __attribute__((ext_vector_type(4))) float f32x4;
typedef __attribute__((ext_vector_type(8))) short bf16x8;

#define F_TOTAL 16384
#define E_DIM   768
#define FFN     3072

static __device__ __forceinline__ unsigned short f2bf(float f) {
    union { float f; unsigned int i; } v; v.f = f;
    unsigned int r = v.i + 0x7FFFu + ((v.i >> 16) & 1u);   // RNE
    return (unsigned short)(r >> 16);
}
static __device__ __forceinline__ void gload16(const void* g, void* l) {
    __builtin_amdgcn_global_load_lds((const __attribute__((address_space(1))) unsigned int*)g,
                                     (__attribute__((address_space(3))) unsigned int*)l,
                                     16, 0, 0);
}

// ---------------- kW2: W2 fp32 -> bf16, pre-swizzled ----------------
__global__ __launch_bounds__(384) void kW2(const float* __restrict__ w2,
                                           unsigned short* __restrict__ w2b) {
    const int n = (int)blockIdx.x;        // 768 rows
    const int c = (int)threadIdx.x;       // 384 chunks of 8
    const float4* src = (const float4*)(w2 + (size_t)n * FFN + c * 8);
    float4 a = src[0], b = src[1];
    bf16x8 v;
    v[0] = (short)f2bf(a.x); v[1] = (short)f2bf(a.y);
    v[2] = (short)f2bf(a.z); v[3] = (short)f2bf(a.w);
    v[4] = (short)f2bf(b.x); v[5] = (short)f2bf(b.y);
    v[6] = (short)f2bf(b.z); v[7] = (short)f2bf(b.w);
    *(bf16x8*)(w2b + (size_t)n * FFN + (size_t)(c ^ (n & 7)) * 8) = v;
}

// ---------------- kP: pack W1 + b1 -> w1p[3072][32] (swizzled) ----------------
__global__ void kP(const float* __restrict__ w1,
                   const float* __restrict__ b1,
                   unsigned short* __restrict__ w1p) {
    int k = blockIdx.x * 256 + threadIdx.x;
    if (k >= FFN) return;
    float r[32];
#pragma unroll
    for (int w = 0; w < 10; ++w) r[w] = w1[k * 10 + w];
    r[10] = b1[k];
#pragma unroll
    for (int w = 11; w < 32; ++w) r[w] = 0.f;
#pragma unroll
    for (int c = 0; c < 4; ++c) {
        bf16x8 v;
#pragma unroll
        for (int e = 0; e < 8; ++e) v[e] = (short)f2bf(r[c * 8 + e]);
        *(bf16x8*)(w1p + (size_t)k * 32 + (size_t)((c ^ (k & 3)) * 8)) = v;
    }
}

// ---------------- kQ: coalesced wave-per-row ---------------------------------
// 1024 blocks x 256 threads (4 waves). Wave owns 4 consecutive rows.
// Wmap [10][768] fp32 staged in LDS (30 KB). Lane l owns x elements
// {4l..4l+3} u {256+4l..} u {512+4l..} (fully coalesced float4 loads).
// Butterfly __shfl_xor reduce for all 10 wires; lanes 0..31 write the full
// padded/swizzled q row (bias slot elem 10 = 1.0, elems 11..31 = 0).
__global__ __launch_bounds__(256) void kQ(const float* __restrict__ x,
                                          const float* __restrict__ wm,
                                          const float* __restrict__ th,
                                          unsigned short* __restrict__ qp) {
    __shared__ float wms[10 * 768];  // 30 KB
    const int tid = (int)threadIdx.x;
    for (int i = tid; i < 10 * 768; i += 256) wms[i] = wm[i];
    __syncthreads();

    const int wv = tid >> 6, l = tid & 63;
    const int mbase = (int)blockIdx.x * 16 + wv * 4;
    const float thv = (l < 10) ? th[l] : 0.f;
    const float cth = __cosf(thv);

#pragma unroll
    for (int r = 0; r < 4; ++r) {
        const int m = mbase + r;
        const float4* xp = (const float4*)(x + (size_t)m * E_DIM);
        const float4 xa = xp[l], xb = xp[64 + l], xc = xp[128 + l];
        float s[10];
#pragma unroll
        for (int w = 0; w < 10; ++w) {
            const float4* wp = (const float4*)(wms + w * E_DIM);
            const float4 wa = wp[l], wb = wp[64 + l], wc = wp[128 + l];
            float t0 = xa.x * wa.x;
            float t1 = xa.y * wa.y;
            t0 = fmaf(xa.z, wa.z, t0); t1 = fmaf(xa.w, wa.w, t1);
            t0 = fmaf(xb.x, wb.x, t0); t1 = fmaf(xb.y, wb.y, t1);
            t0 = fmaf(xb.z, wb.z, t0); t1 = fmaf(xb.w, wb.w, t1);
            t0 = fmaf(xc.x, wc.x, t0); t1 = fmaf(xc.y, wc.y, t1);
            t0 = fmaf(xc.z, wc.z, t0); t1 = fmaf(xc.w, wc.w, t1);
            s[w] = t0 + t1;
        }
#pragma unroll
        for (int w = 0; w < 10; ++w) {
            float v = s[w];
            v += __shfl_xor(v, 1);  v += __shfl_xor(v, 2);  v += __shfl_xor(v, 4);
            v += __shfl_xor(v, 8);  v += __shfl_xor(v, 16); v += __shfl_xor(v, 32);
            s[w] = v;
        }
        if (l < 32) {
            float sv = 0.f;
#pragma unroll
            for (int w = 0; w < 10; ++w) sv = (l == w) ? s[w] : sv;
            float val = (l < 10) ? (cth * __cosf(sv)) : ((l == 10) ? 1.0f : 0.f);
            qp[(size_t)m * 32 + (size_t)((((l >> 3) ^ (m & 3)) * 8) + (l & 7))] = f2bf(val);
        }
    }
}

// ---------------- kG: fused h-compute + main GEMM (unchanged) -----------------
// 512 blocks, 512 threads (8 waves). BM=64, BN=384, BK=64.
// LDS = 48K(w2) + 8K(h) + 4K(q) + 4K(w1) = 64 KiB -> 2 blocks/CU.
__global__ __launch_bounds__(512, 4) void kG(const unsigned short* __restrict__ w2b,
                                             const float* __restrict__ b2,
                                             const unsigned short* __restrict__ qp,
                                             const unsigned short* __restrict__ w1p,
                                             float* __restrict__ outp) {
    __shared__ __align__(16) unsigned short w2s[384 * 64];  // [n][k] swz8 (pre-swizzled src)
    __shared__ __align__(16) unsigned short hs[64 * 64];    // [m][k] swz8
    __shared__ __align__(16) unsigned short qs[64 * 32];    // verbatim pre-swizzled qp rows
    __shared__ __align__(16) unsigned short w1s[64 * 32];   // verbatim pre-swizzled w1p rows

    const int tid = (int)threadIdx.x;
    const int wv = tid >> 6;
    const int l  = tid & 63;
    const int bid = (int)blockIdx.x;
    const int ld  = (bid & 7) * 64 + (bid >> 3);   // bijective XCD-chunked swizzle
    const int m0 = (ld & 255) * 64;
    const int n0 = (ld >> 8) * 384;

    if (wv < 4) {
        const unsigned short* src = qp + (size_t)(m0 + (tid >> 2)) * 32 + (size_t)(tid & 3) * 8;
        gload16(src, qs + (size_t)wv * 512);
    }

    const f32x4 z4 = {0.f, 0.f, 0.f, 0.f};
    f32x4 acc[4][3];
#pragma unroll
    for (int a = 0; a < 4; ++a)
#pragma unroll
        for (int b = 0; b < 3; ++b) acc[a][b] = z4;

    const int mih = wv >> 1;
    const int r_w2 = tid >> 3;
    const int c_w2 = tid & 7;
    bf16x8 aq;

    for (int kt = 0; kt < FFN / 64; ++kt) {
        const int k0 = kt * 64;
        if (wv < 4) {
            const unsigned short* s1 = w1p + (size_t)(k0 + (tid >> 2)) * 32 + (size_t)(tid & 3) * 8;
            gload16(s1, w1s + (size_t)wv * 512);
        }
#pragma unroll
        for (int i = 0; i < 6; ++i) {
            int r = i * 64 + r_w2;
            const unsigned short* s2 = w2b + (size_t)(n0 + r) * FFN + k0 + (size_t)c_w2 * 8;
            gload16(s2, w2s + (size_t)i * 4096 + (size_t)wv * 512);
        }
        __syncthreads();

        if (kt == 0) {
            int qrow = mih * 16 + (l & 15);
            int qch = (l >> 4) ^ (qrow & 3);
            aq = *(const bf16x8*)(qs + qrow * 32 + qch * 8);
        }

        // ---- h phase: h[64][64] = relu(q @ W1c^T + b1) via MFMA ----
#pragma unroll
        for (int j = 0; j < 2; ++j) {
            int ki = (wv * 2 + j) & 3;
            int kw = ki * 16 + (l & 15);
            int cw = (l >> 4) ^ (kw & 3);
            bf16x8 bw = *(const bf16x8*)(w1s + kw * 32 + cw * 8);
            f32x4 hv = __builtin_amdgcn_mfma_f32_16x16x32_bf16(aq, bw, z4, 0, 0, 0);
            int kkc = ki * 16 + (l & 15);
            int mb = mih * 16 + (l >> 4) * 4;
#pragma unroll
            for (int jj = 0; jj < 4; ++jj) {
                int m = mb + jj;
                hs[m * 64 + (((kkc >> 3) ^ (m & 7)) * 8) + (kkc & 7)] =
                    f2bf(fmaxf(hv[jj], 0.f));
            }
        }
        __syncthreads();

        // ---- main phase: acc += h @ W2tile^T ----
#pragma unroll
        for (int kk2 = 0; kk2 < 2; ++kk2) {
            const int kc = kk2 * 4 + (l >> 4);
            bf16x8 af[4];
#pragma unroll
            for (int mi = 0; mi < 4; ++mi) {
                int m = mi * 16 + (l & 15);
                af[mi] = *(const bf16x8*)(hs + m * 64 + ((kc ^ (m & 7)) * 8));
            }
#pragma unroll
            for (int ni = 0; ni < 3; ++ni) {
                int n = wv * 48 + ni * 16 + (l & 15);
                bf16x8 bfr = *(const bf16x8*)(w2s + n * 64 + ((kc ^ (n & 7)) * 8));
#pragma unroll
                for (int mi = 0; mi < 4; ++mi)
                    acc[mi][ni] = __builtin_amdgcn_mfma_f32_16x16x32_bf16(af[mi], bfr, acc[mi][ni], 0, 0, 0);
            }
        }
        __syncthreads();
    }

    // epilogue: + b2, fp32 store
#pragma unroll
    for (int ni = 0; ni < 3; ++ni) {
        int n = n0 + wv * 48 + ni * 16 + (l & 15);
        float b2v = b2[n];
#pragma unroll
        for (int mi = 0; mi < 4; ++mi) {
            int mbase = m0 + mi * 16 + (l >> 4) * 4;
#pragma unroll
            for (int jj = 0; jj < 4; ++jj)
                outp[(size_t)(mbase + jj) * E_DIM + n] = acc[mi][ni][jj] + b2v;
        }
    }
}

extern "C" void kernel_launch(void* const* d_in, const int* in_sizes, int n_in,
                              void* d_out, int out_size, void* d_ws, size_t ws_size,
                              hipStream_t stream) {
    const float* x    = (const float*)d_in[0];
    const float* wmap = (const float*)d_in[1];
    const float* th   = (const float*)d_in[2];
    const float* w1   = (const float*)d_in[3];
    const float* b1   = (const float*)d_in[4];
    const float* w2   = (const float*)d_in[5];
    const float* b2   = (const float*)d_in[6];
    float* out = (float*)d_out;

    unsigned short* qp  = (unsigned short*)d_ws;            // 16384*32 bf16 = 1 MiB
    unsigned short* w1p = qp + (size_t)F_TOTAL * 32;        // 3072*32 bf16 = 192 KiB
    unsigned short* w2b = w1p + (size_t)FFN * 32;           // 768*3072 bf16 = 4.5 MiB

    kW2<<<E_DIM, 384, 0, stream>>>(w2, w2b);
    kP<<<(FFN + 255) / 256, 256, 0, stream>>>(w1, b1, w1p);
    kQ<<<1024, 256, 0, stream>>>(x, wmap, th, qp);
    kG<<<512, 512, 0, stream>>>(w2b, b2, qp, w1p, out);
}